// Round 20
// baseline (187.679 us; speedup 1.0000x reference)
//
#include <hip/hip_runtime.h>
#include <hip/hip_fp16.h>

#define NN 100000
#define NE 1600000
#define NBK 782    // node buckets of 128: ceil(100000/128)
#define MAXB 2560  // padded slots per bucket (mean 2046, +11 sigma)
#define EPB 4096   // edges per phase-1 block
#define NPB 391    // ceil(NE/EPB)

typedef __attribute__((ext_vector_type(8))) _Float16 f16x8;
typedef __attribute__((ext_vector_type(4))) _Float16 f16x4;
typedef __attribute__((ext_vector_type(4))) float f32x4;

// ---------------- phase 1: bucket edges by dst>>7 (and src>>7 for degO) ----
// cursors start at 0 (memset); global slot = b*MAXB + reserved offset.
__global__ __launch_bounds__(256) void phase1_kernel(const int* __restrict__ src,
                                                     const int* __restrict__ dst,
                                                     int* __restrict__ cursorA,
                                                     int* __restrict__ cursorO,
                                                     int* __restrict__ tempA,
                                                     unsigned char* __restrict__ tempO8) {
    __shared__ int cntA[NBK], cntO[NBK];
    const int t = threadIdx.x;
    for (int b = t; b < NBK; b += 256) { cntA[b] = 0; cntO[b] = 0; }
    __syncthreads();
    const int e0 = blockIdx.x * EPB;
    int rD[16], rS[16];
#pragma unroll
    for (int i = 0; i < 16; ++i) {
        int e = e0 + i * 256 + t;
        if (e < NE) {
            rD[i] = atomicAdd(&cntA[dst[e] >> 7], 1);
            rS[i] = atomicAdd(&cntO[src[e] >> 7], 1);
        }
    }
    __syncthreads();
    // reserve global ranges per nonzero bucket; overwrite cnt slot with base
    for (int b = t; b < NBK; b += 256) {
        int c = cntA[b];
        cntA[b] = c ? (b * MAXB + atomicAdd(&cursorA[b], c)) : 0;
        c = cntO[b];
        cntO[b] = c ? (b * MAXB + atomicAdd(&cursorO[b], c)) : 0;
    }
    __syncthreads();
#pragma unroll
    for (int i = 0; i < 16; ++i) {
        int e = e0 + i * 256 + t;
        if (e < NE) {
            int d = dst[e], s = src[e];
            tempA[cntA[d >> 7] + rD[i]] = ((d & 127) << 17) | s;
            tempO8[cntO[s >> 7] + rS[i]] = (unsigned char)(s & 127);
        }
    }
}

// ------ phase 2: per-bucket node grouping + rowext + fp16 x*normO copy -----
// csr_src stays PADDED (bucket b occupies [b*MAXB, b*MAXB+cA)); per-node
// extents written as int2 rowext[node] = {beg, end}.
__global__ __launch_bounds__(256) void phase2_kernel(const int* __restrict__ cursorA,
                                                     const int* __restrict__ cursorO,
                                                     const int* __restrict__ tempA,
                                                     const unsigned char* __restrict__ tempO8,
                                                     const float* __restrict__ x,
                                                     int* __restrict__ csr_src,
                                                     int2* __restrict__ rowext,
                                                     __half* __restrict__ xh) {
    __shared__ int buf[MAXB];
    __shared__ int cnt[128], ex[128], run[128], cntO[128];
    const int b = blockIdx.x;
    const int t = threadIdx.x;
    const int cA = cursorA[b];
    const int cO = cursorO[b];
    const int base = b * MAXB;
    if (t < 128) { cnt[t] = 0; cntO[t] = 0; run[t] = 0; }
    __syncthreads();
    for (int i = t; i < cA; i += 256) {
        int w = tempA[base + i];
        buf[i] = w;
        atomicAdd(&cnt[(w >> 17) & 127], 1);
    }
    for (int i = t; i < cO; i += 256)
        atomicAdd(&cntO[tempO8[base + i]], 1);
    __syncthreads();
    // fp16 copy of x rows for this bucket, normO folded in (rows contiguous)
    {
        int r = t >> 1;
        int node = b * 128 + r;
        if (node < NN) {
            float nO = rsqrtf(fmaxf((float)cntO[r], 1.0f));
            int c0 = (t & 1) * 64;
#pragma unroll
            for (int i = 0; i < 16; ++i) {
                float4 v = *reinterpret_cast<const float4*>(&x[(size_t)node * 128 + c0 + i * 4]);
                __half2 h01 = __floats2half2_rn(v.x * nO, v.y * nO);
                __half2 h23 = __floats2half2_rn(v.z * nO, v.w * nO);
                __half2 hh[2] = {h01, h23};
                *reinterpret_cast<float2*>(&xh[(size_t)node * 128 + c0 + i * 4]) =
                    *reinterpret_cast<float2*>(hh);
            }
        }
    }
    if (t < 128) ex[t] = cnt[t];
    __syncthreads();
    for (int o = 1; o < 128; o <<= 1) {
        int u = (t >= o && t < 128) ? ex[t - o] : 0;
        __syncthreads();
        if (t < 128) ex[t] += u;   // inclusive scan
        __syncthreads();
    }
    if (t < 128) {
        int node = b * 128 + t;
        if (node < NN)
            rowext[node] = make_int2(base + ex[t] - cnt[t], base + ex[t]);
    }
    __syncthreads();
    for (int i = t; i < cA; i += 256) {
        int w = buf[i];
        int n = (w >> 17) & 127;
        int r = atomicAdd(&run[n], 1);
        csr_src[base + ex[n] - cnt[n] + r] = w & 0x1FFFF;
    }
}

// ------ gather (r16 form): 8 warp32/block, fp16 out, int2 extents ---------
__global__ __launch_bounds__(256) void gather_kernel(const __half* __restrict__ xh,
                                                     const int2* __restrict__ rowext,
                                                     const int* __restrict__ csr_src,
                                                     __half* __restrict__ aggh) {
    int node = blockIdx.x * 8 + (threadIdx.x >> 5);
    int lane = threadIdx.x & 31;
    if (node >= NN) return;
    int2 be = rowext[node];
    int beg = be.x, end = be.y;
    float ax = 0.f, ay = 0.f, az = 0.f, aw = 0.f;
    int j = beg;
    for (; j + 4 <= end; j += 4) {
        int s0 = csr_src[j], s1 = csr_src[j + 1], s2 = csr_src[j + 2], s3 = csr_src[j + 3];
        float2 r0 = *reinterpret_cast<const float2*>(&xh[(size_t)s0 * 128 + lane * 4]);
        float2 r1 = *reinterpret_cast<const float2*>(&xh[(size_t)s1 * 128 + lane * 4]);
        float2 r2 = *reinterpret_cast<const float2*>(&xh[(size_t)s2 * 128 + lane * 4]);
        float2 r3 = *reinterpret_cast<const float2*>(&xh[(size_t)s3 * 128 + lane * 4]);
        const __half2* p0 = reinterpret_cast<const __half2*>(&r0);
        const __half2* p1 = reinterpret_cast<const __half2*>(&r1);
        const __half2* p2 = reinterpret_cast<const __half2*>(&r2);
        const __half2* p3 = reinterpret_cast<const __half2*>(&r3);
        float2 l0 = __half22float2(p0[0]), h0 = __half22float2(p0[1]);
        float2 l1 = __half22float2(p1[0]), h1 = __half22float2(p1[1]);
        float2 l2 = __half22float2(p2[0]), h2 = __half22float2(p2[1]);
        float2 l3 = __half22float2(p3[0]), h3 = __half22float2(p3[1]);
        ax += l0.x + l1.x + l2.x + l3.x;
        ay += l0.y + l1.y + l2.y + l3.y;
        az += h0.x + h1.x + h2.x + h3.x;
        aw += h0.y + h1.y + h2.y + h3.y;
    }
    for (; j < end; ++j) {
        int s = csr_src[j];
        float2 r = *reinterpret_cast<const float2*>(&xh[(size_t)s * 128 + lane * 4]);
        const __half2* p = reinterpret_cast<const __half2*>(&r);
        float2 l = __half22float2(p[0]), h = __half22float2(p[1]);
        ax += l.x; ay += l.y; az += h.x; aw += h.y;
    }
    float ni = rsqrtf(fmaxf((float)(end - beg), 1.0f));
    __half2 o01 = __floats2half2_rn(ax * ni, ay * ni);
    __half2 o23 = __floats2half2_rn(az * ni, aw * ni);
    __half2 oo[2] = {o01, o23};
    *reinterpret_cast<float2*>(&aggh[(size_t)node * 256 + lane * 4]) =
        *reinterpret_cast<float2*>(oo);
}

// ---------------- W prep: pack Wc/W1/W2 into fp16 B-fragments -------------
__global__ __launch_bounds__(256) void wprep_kernel(const float* __restrict__ Wc,
                                                    const float* __restrict__ W1,
                                                    const float* __restrict__ W2,
                                                    _Float16* __restrict__ Wf) {
    int t = blockIdx.x * 256 + threadIdx.x;
    if (t >= 3 * 4 * 8 * 64) return;
    int lane = t & 63;
    int ct = (t >> 6) & 7;
    int kt = (t >> 9) & 3;
    int layer = t >> 11;
    const float* W = (layer == 0) ? Wc : (layer == 1) ? W1 : W2;
    int c = ct * 16 + (lane & 15);
    int kbase = kt * 32 + (lane >> 4) * 8;
    f16x8 v;
#pragma unroll
    for (int j = 0; j < 8; ++j)
        v[j] = (_Float16)W[(size_t)(kbase + j) * 128 + c];
    reinterpret_cast<f16x8*>(Wf)[t] = v;
}

// ---------------- fused 3-layer MLP — fp16 single-term, 12-step ring ------
struct MlpState {
    f32x4 acc[8];
    float bv[3][8];
};

#define ISSUE_CHUNK(G, SLOT)                                                    \
    {                                                                           \
        _Pragma("unroll") for (int i = 0; i < 2; ++i) {                         \
            int s = wv * 2 + i;                                                 \
            size_t goff = ((size_t)((G)*8 + s)) * 1024 + (size_t)lane * 16;     \
            __builtin_amdgcn_global_load_lds(                                   \
                (const __attribute__((address_space(1))) unsigned int*)(Wb + goff), \
                (__attribute__((address_space(3))) unsigned int*)(&WL[SLOT][s * 1024]), \
                16, 0, 0);                                                      \
        }                                                                       \
    }

template <int C>
__device__ __forceinline__ void mstep(const char* __restrict__ Wb,
                                      char (&WL)[5][8192],
                                      _Float16 (&HS)[64][136],
                                      MlpState& st,
                                      float* __restrict__ Cout, int n, int row0,
                                      int lane, int wv, int mrow, int kg) {
    constexpr int layer = C >> 2;
    constexpr int kt = C & 3;
    constexpr int VM = (C <= 8) ? 6 : 2 * (11 - C);   // exact outstanding count

    asm volatile("s_waitcnt vmcnt(%0)" ::"i"(VM) : "memory");
    __builtin_amdgcn_s_barrier();

    if constexpr (C + 4 < 12) {
        ISSUE_CHUNK(C + 4, (C + 4) % 5)
    }

    if constexpr (kt == 0) {
#pragma unroll
        for (int i = 0; i < 8; ++i) st.acc[i] = (f32x4){0.f, 0.f, 0.f, 0.f};
    }
    f16x8 a = *reinterpret_cast<const f16x8*>(&HS[wv * 16 + mrow][kt * 32 + kg * 8]);

#pragma unroll
    for (int ct = 0; ct < 8; ++ct) {
        f16x8 w = *reinterpret_cast<const f16x8*>(&WL[C % 5][(ct * 64 + lane) * 16]);
        st.acc[ct] = __builtin_amdgcn_mfma_f32_16x16x32_f16(a, w, st.acc[ct], 0, 0, 0);
    }

    if constexpr (kt == 3) {
        if constexpr (layer < 2) {
#pragma unroll
            for (int ct = 0; ct < 8; ++ct)
#pragma unroll
                for (int r = 0; r < 4; ++r)
                    HS[wv * 16 + kg * 4 + r][ct * 16 + mrow] =
                        (_Float16)fmaxf(st.acc[ct][r] + st.bv[layer][ct], 0.f);
            asm volatile("s_waitcnt lgkmcnt(0)" ::: "memory");
        } else {
#pragma unroll
            for (int ct = 0; ct < 8; ++ct)
#pragma unroll
                for (int r = 0; r < 4; ++r) {
                    int grow = row0 + wv * 16 + kg * 4 + r;
                    if (grow < n)
                        Cout[(size_t)grow * 128 + ct * 16 + mrow] = st.acc[ct][r] + st.bv[2][ct];
                }
        }
    }
}

__global__ __launch_bounds__(256, 2) void mlp_mfma(const __half* __restrict__ Ah,
                                                   const _Float16* __restrict__ Wf,
                                                   const float* __restrict__ bc,
                                                   const float* __restrict__ b1,
                                                   const float* __restrict__ b2,
                                                   float* __restrict__ C, int n) {
    __shared__ _Float16 HS[64][136];
    __shared__ char WL[5][8192];
    const int tid = threadIdx.x;
    const int lane = tid & 63;
    const int wv = tid >> 6;
    const int row0 = blockIdx.x * 64;
    const int mrow = lane & 15;
    const int kg = lane >> 4;
    const char* Wb = (const char*)Wf;

    ISSUE_CHUNK(0, 0)
    ISSUE_CHUNK(1, 1)
    ISSUE_CHUNK(2, 2)
    ISSUE_CHUNK(3, 3)

    // stage 64 rows of A (already fp16; aggh row r at half-index r*256)
    {
        int r = tid >> 5;
        int c4 = (tid & 31) * 4;
#pragma unroll
        for (int i = 0; i < 8; ++i) {
            int row = i * 8 + r;
            int grow = row0 + row;
            f16x4 hv = (f16x4){(_Float16)0.f, (_Float16)0.f, (_Float16)0.f, (_Float16)0.f};
            if (grow < n)
                hv = *reinterpret_cast<const f16x4*>(&Ah[(size_t)grow * 256 + c4]);
            *reinterpret_cast<f16x4*>(&HS[row][c4]) = hv;
        }
    }
    MlpState st;
#pragma unroll
    for (int ct = 0; ct < 8; ++ct) {
        st.bv[0][ct] = bc[ct * 16 + mrow];
        st.bv[1][ct] = b1[ct * 16 + mrow];
        st.bv[2][ct] = b2[ct * 16 + mrow];
    }
    __syncthreads();   // staging reads drained before any in-place C write

    mstep<0>(Wb, WL, HS, st, C, n, row0, lane, wv, mrow, kg);
    mstep<1>(Wb, WL, HS, st, C, n, row0, lane, wv, mrow, kg);
    mstep<2>(Wb, WL, HS, st, C, n, row0, lane, wv, mrow, kg);
    mstep<3>(Wb, WL, HS, st, C, n, row0, lane, wv, mrow, kg);
    mstep<4>(Wb, WL, HS, st, C, n, row0, lane, wv, mrow, kg);
    mstep<5>(Wb, WL, HS, st, C, n, row0, lane, wv, mrow, kg);
    mstep<6>(Wb, WL, HS, st, C, n, row0, lane, wv, mrow, kg);
    mstep<7>(Wb, WL, HS, st, C, n, row0, lane, wv, mrow, kg);
    mstep<8>(Wb, WL, HS, st, C, n, row0, lane, wv, mrow, kg);
    mstep<9>(Wb, WL, HS, st, C, n, row0, lane, wv, mrow, kg);
    mstep<10>(Wb, WL, HS, st, C, n, row0, lane, wv, mrow, kg);
    mstep<11>(Wb, WL, HS, st, C, n, row0, lane, wv, mrow, kg);
}

extern "C" void kernel_launch(void* const* d_in, const int* in_sizes, int n_in,
                              void* d_out, int out_size, void* d_ws, size_t ws_size,
                              hipStream_t stream) {
    const float* x  = (const float*)d_in[0];
    const int*  src = (const int*)d_in[1];
    const int*  dst = (const int*)d_in[2];
    const float* Wc = (const float*)d_in[3];
    const float* bc = (const float*)d_in[4];
    const float* W1 = (const float*)d_in[5];
    const float* b1 = (const float*)d_in[6];
    const float* W2 = (const float*)d_in[7];
    const float* b2 = (const float*)d_in[8];
    float* out = (float*)d_out;
    __half* aggh = (__half*)d_out;   // fp16 agg interleaved: row r at half r*256

    char* p = (char*)d_ws;
    _Float16* Wf = (_Float16*)p;        p += 196608;                        // uses 98304
    __half* xh = (__half*)p;            p += (size_t)NN * 128 * 2;          // 25.6 MB
    int* tempA = (int*)p;               p += (size_t)NBK * MAXB * 4;        // 8.0 MB
    unsigned char* tempO8 = (unsigned char*)p; p += (size_t)NBK * MAXB;     // 2.0 MB
    int* cursorA  = (int*)p;            p += (size_t)NBK * 4;
    int* cursorO  = (int*)p;            p += (size_t)NBK * 4;
    int2* rowext  = (int2*)p;           p += (size_t)NN * 8;
    int* csr_src  = (int*)p;            // NBK*MAXB ints (padded, 8 MB)

    wprep_kernel<<<24, 256, 0, stream>>>(Wc, W1, W2, Wf);
    hipMemsetAsync(cursorA, 0, (size_t)2 * NBK * sizeof(int), stream);
    phase1_kernel<<<NPB, 256, 0, stream>>>(src, dst, cursorA, cursorO, tempA, tempO8);
    phase2_kernel<<<NBK, 256, 0, stream>>>(cursorA, cursorO, tempA, tempO8,
                                           x, csr_src, rowext, xh);

    // agg (norms folded) -> fp16, interleaved into d_out
    gather_kernel<<<(NN + 7) / 8, 256, 0, stream>>>(xh, rowext, csr_src, aggh);

    // fused 3-layer MLP via fp16 MFMA -> d_out f32 (block-local in-place)
    mlp_mfma<<<(NN + 63) / 64, 256, 0, stream>>>(aggh, Wf, bc, b1, b2, out, NN);
}

// Round 21
// 179.134 us; speedup vs baseline: 1.0477x; 1.0477x over previous
//
#include <hip/hip_runtime.h>
#include <hip/hip_fp16.h>

#define NN 100000
#define NE 1600000
#define NBK 782    // node buckets of 128: ceil(100000/128)
#define MAXB 2560  // padded slots per bucket (mean 2046, +11 sigma)
#define EPB 8192   // edges per phase-1 block
#define NPB 196    // ceil(NE/EPB)

typedef __attribute__((ext_vector_type(8))) _Float16 f16x8;
typedef __attribute__((ext_vector_type(4))) _Float16 f16x4;
typedef __attribute__((ext_vector_type(4))) float f32x4;

// ---- phase 1 v2: LDS counting-sort per block, coalesced run writes -------
// cursors start at 0 (memset); bucket b's global region = [b*MAXB, ...).
__global__ __launch_bounds__(256) void phase1_kernel(const int* __restrict__ src,
                                                     const int* __restrict__ dst,
                                                     int* __restrict__ cursorA,
                                                     int* __restrict__ cursorO,
                                                     int* __restrict__ tempA,
                                                     unsigned char* __restrict__ tempO8) {
    __shared__ int cntA[1024];          // counts -> exclusive positions (pad)
    __shared__ int cntO[1024];
    __shared__ int gofsA[NBK];          // global_base - lds_ex  per bucket
    __shared__ int gofsO[NBK];
    __shared__ int runA[NBK];
    __shared__ int scanT[256];
    __shared__ int edgeBuf[EPB];        // 32 KB (reused as byte buf for O)
    __shared__ unsigned short bkt16[EPB]; // 16 KB

    const int t = threadIdx.x;
    const int e0 = blockIdx.x * EPB;
    const int nE = min(EPB, NE - e0);

    for (int i = t; i < 1024; i += 256) { cntA[i] = 0; cntO[i] = 0; }
    __syncthreads();
    for (int i = t; i < nE; i += 256) {
        atomicAdd(&cntA[dst[e0 + i] >> 7], 1);
        atomicAdd(&cntO[src[e0 + i] >> 7], 1);
    }
    __syncthreads();

    // ---- scan A (1024 bins, 4 per thread) ----
    int a[4], sA = 0;
#pragma unroll
    for (int k = 0; k < 4; ++k) { a[k] = cntA[4 * t + k]; sA += a[k]; }
    scanT[t] = sA;
    __syncthreads();
    for (int o = 1; o < 256; o <<= 1) {
        int u = (t >= o) ? scanT[t - o] : 0;
        __syncthreads();
        scanT[t] += u;
        __syncthreads();
    }
    {
        int r = scanT[t] - sA;
#pragma unroll
        for (int k = 0; k < 4; ++k) { int c = a[k]; cntA[4 * t + k] = r; r += c; }
    }
    __syncthreads();
    // ---- scan O ----
    int o4[4], sO = 0;
#pragma unroll
    for (int k = 0; k < 4; ++k) { o4[k] = cntO[4 * t + k]; sO += o4[k]; }
    scanT[t] = sO;
    __syncthreads();
    for (int o = 1; o < 256; o <<= 1) {
        int u = (t >= o) ? scanT[t - o] : 0;
        __syncthreads();
        scanT[t] += u;
        __syncthreads();
    }
    {
        int r = scanT[t] - sO;
#pragma unroll
        for (int k = 0; k < 4; ++k) { int c = o4[k]; cntO[4 * t + k] = r; r += c; }
    }
    __syncthreads();

    // ---- reserve global ranges; gofs = gbase - lds_ex ----
    for (int b = t; b < NBK; b += 256) {
        int ex = cntA[b], c = cntA[b + 1] - ex;
        gofsA[b] = c ? (b * MAXB + atomicAdd(&cursorA[b], c) - ex) : 0;
        int exo = cntO[b], co = cntO[b + 1] - exo;
        gofsO[b] = co ? (b * MAXB + atomicAdd(&cursorO[b], co) - exo) : 0;
        runA[b] = 0;
    }
    __syncthreads();

    // ---- stage A: scatter into LDS sorted by bucket, then run-write ----
    for (int i = t; i < nE; i += 256) {
        int d = dst[e0 + i], s = src[e0 + i];
        int b = d >> 7;
        int pos = cntA[b] + atomicAdd(&runA[b], 1);
        edgeBuf[pos] = ((d & 127) << 17) | s;
        bkt16[pos] = (unsigned short)b;
    }
    __syncthreads();
    for (int i = t; i < nE; i += 256) {
        int b = bkt16[i];
        tempA[gofsA[b] + i] = edgeBuf[i];
    }
    __syncthreads();
    for (int b = t; b < NBK; b += 256) runA[b] = 0;
    __syncthreads();

    // ---- stage O: same for src bytes (reuse edgeBuf as bytes) ----
    unsigned char* byteBuf = (unsigned char*)edgeBuf;
    for (int i = t; i < nE; i += 256) {
        int s = src[e0 + i];
        int b = s >> 7;
        int pos = cntO[b] + atomicAdd(&runA[b], 1);
        byteBuf[pos] = (unsigned char)(s & 127);
        bkt16[pos] = (unsigned short)b;
    }
    __syncthreads();
    for (int i = t; i < nE; i += 256) {
        int b = bkt16[i];
        tempO8[gofsO[b] + i] = byteBuf[i];
    }
}

// ------ phase 2: per-bucket node grouping + rowext + fp16 x*normO copy -----
__global__ __launch_bounds__(256) void phase2_kernel(const int* __restrict__ cursorA,
                                                     const int* __restrict__ cursorO,
                                                     const int* __restrict__ tempA,
                                                     const unsigned char* __restrict__ tempO8,
                                                     const float* __restrict__ x,
                                                     int* __restrict__ csr_src,
                                                     int2* __restrict__ rowext,
                                                     __half* __restrict__ xh) {
    __shared__ int buf[MAXB];
    __shared__ int cnt[128], ex[128], run[128], cntO[128];
    const int b = blockIdx.x;
    const int t = threadIdx.x;
    const int cA = cursorA[b];
    const int cO = cursorO[b];
    const int base = b * MAXB;
    if (t < 128) { cnt[t] = 0; cntO[t] = 0; run[t] = 0; }
    __syncthreads();
    for (int i = t; i < cA; i += 256) {
        int w = tempA[base + i];
        buf[i] = w;
        atomicAdd(&cnt[(w >> 17) & 127], 1);
    }
    for (int i = t; i < cO; i += 256)
        atomicAdd(&cntO[tempO8[base + i]], 1);
    __syncthreads();
    {
        int r = t >> 1;
        int node = b * 128 + r;
        if (node < NN) {
            float nO = rsqrtf(fmaxf((float)cntO[r], 1.0f));
            int c0 = (t & 1) * 64;
#pragma unroll
            for (int i = 0; i < 16; ++i) {
                float4 v = *reinterpret_cast<const float4*>(&x[(size_t)node * 128 + c0 + i * 4]);
                __half2 h01 = __floats2half2_rn(v.x * nO, v.y * nO);
                __half2 h23 = __floats2half2_rn(v.z * nO, v.w * nO);
                __half2 hh[2] = {h01, h23};
                *reinterpret_cast<float2*>(&xh[(size_t)node * 128 + c0 + i * 4]) =
                    *reinterpret_cast<float2*>(hh);
            }
        }
    }
    if (t < 128) ex[t] = cnt[t];
    __syncthreads();
    for (int o = 1; o < 128; o <<= 1) {
        int u = (t >= o && t < 128) ? ex[t - o] : 0;
        __syncthreads();
        if (t < 128) ex[t] += u;   // inclusive scan
        __syncthreads();
    }
    if (t < 128) {
        int node = b * 128 + t;
        if (node < NN)
            rowext[node] = make_int2(base + ex[t] - cnt[t], base + ex[t]);
    }
    __syncthreads();
    for (int i = t; i < cA; i += 256) {
        int w = buf[i];
        int n = (w >> 17) & 127;
        int r = atomicAdd(&run[n], 1);
        csr_src[base + ex[n] - cnt[n] + r] = w & 0x1FFFF;
    }
}

// ------ gather: 8 warp32/block, fp16 out, int2 extents --------------------
__global__ __launch_bounds__(256) void gather_kernel(const __half* __restrict__ xh,
                                                     const int2* __restrict__ rowext,
                                                     const int* __restrict__ csr_src,
                                                     __half* __restrict__ aggh) {
    int node = blockIdx.x * 8 + (threadIdx.x >> 5);
    int lane = threadIdx.x & 31;
    if (node >= NN) return;
    int2 be = rowext[node];
    int beg = be.x, end = be.y;
    float ax = 0.f, ay = 0.f, az = 0.f, aw = 0.f;
    int j = beg;
    for (; j + 4 <= end; j += 4) {
        int s0 = csr_src[j], s1 = csr_src[j + 1], s2 = csr_src[j + 2], s3 = csr_src[j + 3];
        float2 r0 = *reinterpret_cast<const float2*>(&xh[(size_t)s0 * 128 + lane * 4]);
        float2 r1 = *reinterpret_cast<const float2*>(&xh[(size_t)s1 * 128 + lane * 4]);
        float2 r2 = *reinterpret_cast<const float2*>(&xh[(size_t)s2 * 128 + lane * 4]);
        float2 r3 = *reinterpret_cast<const float2*>(&xh[(size_t)s3 * 128 + lane * 4]);
        const __half2* p0 = reinterpret_cast<const __half2*>(&r0);
        const __half2* p1 = reinterpret_cast<const __half2*>(&r1);
        const __half2* p2 = reinterpret_cast<const __half2*>(&r2);
        const __half2* p3 = reinterpret_cast<const __half2*>(&r3);
        float2 l0 = __half22float2(p0[0]), h0 = __half22float2(p0[1]);
        float2 l1 = __half22float2(p1[0]), h1 = __half22float2(p1[1]);
        float2 l2 = __half22float2(p2[0]), h2 = __half22float2(p2[1]);
        float2 l3 = __half22float2(p3[0]), h3 = __half22float2(p3[1]);
        ax += l0.x + l1.x + l2.x + l3.x;
        ay += l0.y + l1.y + l2.y + l3.y;
        az += h0.x + h1.x + h2.x + h3.x;
        aw += h0.y + h1.y + h2.y + h3.y;
    }
    for (; j < end; ++j) {
        int s = csr_src[j];
        float2 r = *reinterpret_cast<const float2*>(&xh[(size_t)s * 128 + lane * 4]);
        const __half2* p = reinterpret_cast<const __half2*>(&r);
        float2 l = __half22float2(p[0]), h = __half22float2(p[1]);
        ax += l.x; ay += l.y; az += h.x; aw += h.y;
    }
    float ni = rsqrtf(fmaxf((float)(end - beg), 1.0f));
    __half2 o01 = __floats2half2_rn(ax * ni, ay * ni);
    __half2 o23 = __floats2half2_rn(az * ni, aw * ni);
    __half2 oo[2] = {o01, o23};
    *reinterpret_cast<float2*>(&aggh[(size_t)node * 256 + lane * 4]) =
        *reinterpret_cast<float2*>(oo);
}

// ---------------- W prep: pack Wc/W1/W2 into fp16 B-fragments -------------
__global__ __launch_bounds__(256) void wprep_kernel(const float* __restrict__ Wc,
                                                    const float* __restrict__ W1,
                                                    const float* __restrict__ W2,
                                                    _Float16* __restrict__ Wf) {
    int t = blockIdx.x * 256 + threadIdx.x;
    if (t >= 3 * 4 * 8 * 64) return;
    int lane = t & 63;
    int ct = (t >> 6) & 7;
    int kt = (t >> 9) & 3;
    int layer = t >> 11;
    const float* W = (layer == 0) ? Wc : (layer == 1) ? W1 : W2;
    int c = ct * 16 + (lane & 15);
    int kbase = kt * 32 + (lane >> 4) * 8;
    f16x8 v;
#pragma unroll
    for (int j = 0; j < 8; ++j)
        v[j] = (_Float16)W[(size_t)(kbase + j) * 128 + c];
    reinterpret_cast<f16x8*>(Wf)[t] = v;
}

// ---------------- fused 3-layer MLP — fp16 single-term, 12-step ring ------
struct MlpState {
    f32x4 acc[8];
    float bv[3][8];
};

#define ISSUE_CHUNK(G, SLOT)                                                    \
    {                                                                           \
        _Pragma("unroll") for (int i = 0; i < 2; ++i) {                         \
            int s = wv * 2 + i;                                                 \
            size_t goff = ((size_t)((G)*8 + s)) * 1024 + (size_t)lane * 16;     \
            __builtin_amdgcn_global_load_lds(                                   \
                (const __attribute__((address_space(1))) unsigned int*)(Wb + goff), \
                (__attribute__((address_space(3))) unsigned int*)(&WL[SLOT][s * 1024]), \
                16, 0, 0);                                                      \
        }                                                                       \
    }

template <int C>
__device__ __forceinline__ void mstep(const char* __restrict__ Wb,
                                      char (&WL)[5][8192],
                                      _Float16 (&HS)[64][136],
                                      MlpState& st,
                                      float* __restrict__ Cout, int n, int row0,
                                      int lane, int wv, int mrow, int kg) {
    constexpr int layer = C >> 2;
    constexpr int kt = C & 3;
    constexpr int VM = (C <= 8) ? 6 : 2 * (11 - C);   // exact outstanding count

    asm volatile("s_waitcnt vmcnt(%0)" ::"i"(VM) : "memory");
    __builtin_amdgcn_s_barrier();

    if constexpr (C + 4 < 12) {
        ISSUE_CHUNK(C + 4, (C + 4) % 5)
    }

    if constexpr (kt == 0) {
#pragma unroll
        for (int i = 0; i < 8; ++i) st.acc[i] = (f32x4){0.f, 0.f, 0.f, 0.f};
    }
    f16x8 a = *reinterpret_cast<const f16x8*>(&HS[wv * 16 + mrow][kt * 32 + kg * 8]);

#pragma unroll
    for (int ct = 0; ct < 8; ++ct) {
        f16x8 w = *reinterpret_cast<const f16x8*>(&WL[C % 5][(ct * 64 + lane) * 16]);
        st.acc[ct] = __builtin_amdgcn_mfma_f32_16x16x32_f16(a, w, st.acc[ct], 0, 0, 0);
    }

    if constexpr (kt == 3) {
        if constexpr (layer < 2) {
#pragma unroll
            for (int ct = 0; ct < 8; ++ct)
#pragma unroll
                for (int r = 0; r < 4; ++r)
                    HS[wv * 16 + kg * 4 + r][ct * 16 + mrow] =
                        (_Float16)fmaxf(st.acc[ct][r] + st.bv[layer][ct], 0.f);
            asm volatile("s_waitcnt lgkmcnt(0)" ::: "memory");
        } else {
#pragma unroll
            for (int ct = 0; ct < 8; ++ct)
#pragma unroll
                for (int r = 0; r < 4; ++r) {
                    int grow = row0 + wv * 16 + kg * 4 + r;
                    if (grow < n)
                        Cout[(size_t)grow * 128 + ct * 16 + mrow] = st.acc[ct][r] + st.bv[2][ct];
                }
        }
    }
}

__global__ __launch_bounds__(256, 2) void mlp_mfma(const __half* __restrict__ Ah,
                                                   const _Float16* __restrict__ Wf,
                                                   const float* __restrict__ bc,
                                                   const float* __restrict__ b1,
                                                   const float* __restrict__ b2,
                                                   float* __restrict__ C, int n) {
    __shared__ _Float16 HS[64][136];
    __shared__ char WL[5][8192];
    const int tid = threadIdx.x;
    const int lane = tid & 63;
    const int wv = tid >> 6;
    const int row0 = blockIdx.x * 64;
    const int mrow = lane & 15;
    const int kg = lane >> 4;
    const char* Wb = (const char*)Wf;

    ISSUE_CHUNK(0, 0)
    ISSUE_CHUNK(1, 1)
    ISSUE_CHUNK(2, 2)
    ISSUE_CHUNK(3, 3)

    // stage 64 rows of A (already fp16; aggh row r at half-index r*256)
    {
        int r = tid >> 5;
        int c4 = (tid & 31) * 4;
#pragma unroll
        for (int i = 0; i < 8; ++i) {
            int row = i * 8 + r;
            int grow = row0 + row;
            f16x4 hv = (f16x4){(_Float16)0.f, (_Float16)0.f, (_Float16)0.f, (_Float16)0.f};
            if (grow < n)
                hv = *reinterpret_cast<const f16x4*>(&Ah[(size_t)grow * 256 + c4]);
            *reinterpret_cast<f16x4*>(&HS[row][c4]) = hv;
        }
    }
    MlpState st;
#pragma unroll
    for (int ct = 0; ct < 8; ++ct) {
        st.bv[0][ct] = bc[ct * 16 + mrow];
        st.bv[1][ct] = b1[ct * 16 + mrow];
        st.bv[2][ct] = b2[ct * 16 + mrow];
    }
    __syncthreads();   // staging reads drained before any in-place C write

    mstep<0>(Wb, WL, HS, st, C, n, row0, lane, wv, mrow, kg);
    mstep<1>(Wb, WL, HS, st, C, n, row0, lane, wv, mrow, kg);
    mstep<2>(Wb, WL, HS, st, C, n, row0, lane, wv, mrow, kg);
    mstep<3>(Wb, WL, HS, st, C, n, row0, lane, wv, mrow, kg);
    mstep<4>(Wb, WL, HS, st, C, n, row0, lane, wv, mrow, kg);
    mstep<5>(Wb, WL, HS, st, C, n, row0, lane, wv, mrow, kg);
    mstep<6>(Wb, WL, HS, st, C, n, row0, lane, wv, mrow, kg);
    mstep<7>(Wb, WL, HS, st, C, n, row0, lane, wv, mrow, kg);
    mstep<8>(Wb, WL, HS, st, C, n, row0, lane, wv, mrow, kg);
    mstep<9>(Wb, WL, HS, st, C, n, row0, lane, wv, mrow, kg);
    mstep<10>(Wb, WL, HS, st, C, n, row0, lane, wv, mrow, kg);
    mstep<11>(Wb, WL, HS, st, C, n, row0, lane, wv, mrow, kg);
}

extern "C" void kernel_launch(void* const* d_in, const int* in_sizes, int n_in,
                              void* d_out, int out_size, void* d_ws, size_t ws_size,
                              hipStream_t stream) {
    const float* x  = (const float*)d_in[0];
    const int*  src = (const int*)d_in[1];
    const int*  dst = (const int*)d_in[2];
    const float* Wc = (const float*)d_in[3];
    const float* bc = (const float*)d_in[4];
    const float* W1 = (const float*)d_in[5];
    const float* b1 = (const float*)d_in[6];
    const float* W2 = (const float*)d_in[7];
    const float* b2 = (const float*)d_in[8];
    float* out = (float*)d_out;
    __half* aggh = (__half*)d_out;   // fp16 agg interleaved: row r at half r*256

    char* p = (char*)d_ws;
    _Float16* Wf = (_Float16*)p;        p += 196608;                        // uses 98304
    __half* xh = (__half*)p;            p += (size_t)NN * 128 * 2;          // 25.6 MB
    int* tempA = (int*)p;               p += (size_t)NBK * MAXB * 4;        // 8.0 MB
    unsigned char* tempO8 = (unsigned char*)p; p += (size_t)NBK * MAXB;     // 2.0 MB
    int* cursorA  = (int*)p;            p += (size_t)NBK * 4;
    int* cursorO  = (int*)p;            p += (size_t)NBK * 4;
    int2* rowext  = (int2*)p;           p += (size_t)NN * 8;
    int* csr_src  = (int*)p;            // NBK*MAXB ints (padded, 8 MB)

    wprep_kernel<<<24, 256, 0, stream>>>(Wc, W1, W2, Wf);
    hipMemsetAsync(cursorA, 0, (size_t)2 * NBK * sizeof(int), stream);
    phase1_kernel<<<NPB, 256, 0, stream>>>(src, dst, cursorA, cursorO, tempA, tempO8);
    phase2_kernel<<<NBK, 256, 0, stream>>>(cursorA, cursorO, tempA, tempO8,
                                           x, csr_src, rowext, xh);

    // agg (norms folded) -> fp16, interleaved into d_out
    gather_kernel<<<(NN + 7) / 8, 256, 0, stream>>>(xh, rowext, csr_src, aggh);

    // fused 3-layer MLP via fp16 MFMA -> d_out f32 (block-local in-place)
    mlp_mfma<<<(NN + 63) / 64, 256, 0, stream>>>(aggh, Wf, bc, b1, b2, out, NN);
}

// Round 22
// 173.489 us; speedup vs baseline: 1.0818x; 1.0325x over previous
//
#include <hip/hip_runtime.h>
#include <hip/hip_fp16.h>

#define NN 100000
#define NE 1600000
#define NBK 782    // node buckets of 128: ceil(100000/128)
#define MAXB 2560  // padded slots per bucket (mean 2046, +11 sigma)
#define EPB 8192   // edges per phase-1 block
#define NPB 196    // ceil(NE/EPB)

typedef __attribute__((ext_vector_type(8))) _Float16 f16x8;
typedef __attribute__((ext_vector_type(4))) _Float16 f16x4;
typedef __attribute__((ext_vector_type(4))) float f32x4;

// ---- phase 1 v2: LDS counting-sort per block, coalesced run writes -------
__global__ __launch_bounds__(256) void phase1_kernel(const int* __restrict__ src,
                                                     const int* __restrict__ dst,
                                                     int* __restrict__ cursorA,
                                                     int* __restrict__ cursorO,
                                                     int* __restrict__ tempA,
                                                     unsigned char* __restrict__ tempO8) {
    __shared__ int cntA[1024];
    __shared__ int cntO[1024];
    __shared__ int gofsA[NBK];
    __shared__ int gofsO[NBK];
    __shared__ int runA[NBK];
    __shared__ int scanT[256];
    __shared__ int edgeBuf[EPB];
    __shared__ unsigned short bkt16[EPB];

    const int t = threadIdx.x;
    const int e0 = blockIdx.x * EPB;
    const int nE = min(EPB, NE - e0);

    for (int i = t; i < 1024; i += 256) { cntA[i] = 0; cntO[i] = 0; }
    __syncthreads();
    for (int i = t; i < nE; i += 256) {
        atomicAdd(&cntA[dst[e0 + i] >> 7], 1);
        atomicAdd(&cntO[src[e0 + i] >> 7], 1);
    }
    __syncthreads();

    int a[4], sA = 0;
#pragma unroll
    for (int k = 0; k < 4; ++k) { a[k] = cntA[4 * t + k]; sA += a[k]; }
    scanT[t] = sA;
    __syncthreads();
    for (int o = 1; o < 256; o <<= 1) {
        int u = (t >= o) ? scanT[t - o] : 0;
        __syncthreads();
        scanT[t] += u;
        __syncthreads();
    }
    {
        int r = scanT[t] - sA;
#pragma unroll
        for (int k = 0; k < 4; ++k) { int c = a[k]; cntA[4 * t + k] = r; r += c; }
    }
    __syncthreads();
    int o4[4], sO = 0;
#pragma unroll
    for (int k = 0; k < 4; ++k) { o4[k] = cntO[4 * t + k]; sO += o4[k]; }
    scanT[t] = sO;
    __syncthreads();
    for (int o = 1; o < 256; o <<= 1) {
        int u = (t >= o) ? scanT[t - o] : 0;
        __syncthreads();
        scanT[t] += u;
        __syncthreads();
    }
    {
        int r = scanT[t] - sO;
#pragma unroll
        for (int k = 0; k < 4; ++k) { int c = o4[k]; cntO[4 * t + k] = r; r += c; }
    }
    __syncthreads();

    for (int b = t; b < NBK; b += 256) {
        int ex = cntA[b], c = cntA[b + 1] - ex;
        gofsA[b] = c ? (b * MAXB + atomicAdd(&cursorA[b], c) - ex) : 0;
        int exo = cntO[b], co = cntO[b + 1] - exo;
        gofsO[b] = co ? (b * MAXB + atomicAdd(&cursorO[b], co) - exo) : 0;
        runA[b] = 0;
    }
    __syncthreads();

    for (int i = t; i < nE; i += 256) {
        int d = dst[e0 + i], s = src[e0 + i];
        int b = d >> 7;
        int pos = cntA[b] + atomicAdd(&runA[b], 1);
        edgeBuf[pos] = ((d & 127) << 17) | s;
        bkt16[pos] = (unsigned short)b;
    }
    __syncthreads();
    for (int i = t; i < nE; i += 256) {
        int b = bkt16[i];
        tempA[gofsA[b] + i] = edgeBuf[i];
    }
    __syncthreads();
    for (int b = t; b < NBK; b += 256) runA[b] = 0;
    __syncthreads();

    unsigned char* byteBuf = (unsigned char*)edgeBuf;
    for (int i = t; i < nE; i += 256) {
        int s = src[e0 + i];
        int b = s >> 7;
        int pos = cntO[b] + atomicAdd(&runA[b], 1);
        byteBuf[pos] = (unsigned char)(s & 127);
        bkt16[pos] = (unsigned short)b;
    }
    __syncthreads();
    for (int i = t; i < nE; i += 256) {
        int b = bkt16[i];
        tempO8[gofsO[b] + i] = byteBuf[i];
    }
}

// ------ phase 2: per-bucket node grouping + rowext + fp16 x*normO copy -----
__global__ __launch_bounds__(256) void phase2_kernel(const int* __restrict__ cursorA,
                                                     const int* __restrict__ cursorO,
                                                     const int* __restrict__ tempA,
                                                     const unsigned char* __restrict__ tempO8,
                                                     const float* __restrict__ x,
                                                     int* __restrict__ csr_src,
                                                     int2* __restrict__ rowext,
                                                     __half* __restrict__ xh) {
    __shared__ int buf[MAXB];
    __shared__ int cnt[128], ex[128], run[128], cntO[128];
    const int b = blockIdx.x;
    const int t = threadIdx.x;
    const int cA = cursorA[b];
    const int cO = cursorO[b];
    const int base = b * MAXB;
    if (t < 128) { cnt[t] = 0; cntO[t] = 0; run[t] = 0; }
    __syncthreads();
    for (int i = t; i < cA; i += 256) {
        int w = tempA[base + i];
        buf[i] = w;
        atomicAdd(&cnt[(w >> 17) & 127], 1);
    }
    for (int i = t; i < cO; i += 256)
        atomicAdd(&cntO[tempO8[base + i]], 1);
    __syncthreads();
    {
        int r = t >> 1;
        int node = b * 128 + r;
        if (node < NN) {
            float nO = rsqrtf(fmaxf((float)cntO[r], 1.0f));
            int c0 = (t & 1) * 64;
#pragma unroll
            for (int i = 0; i < 16; ++i) {
                float4 v = *reinterpret_cast<const float4*>(&x[(size_t)node * 128 + c0 + i * 4]);
                __half2 h01 = __floats2half2_rn(v.x * nO, v.y * nO);
                __half2 h23 = __floats2half2_rn(v.z * nO, v.w * nO);
                __half2 hh[2] = {h01, h23};
                *reinterpret_cast<float2*>(&xh[(size_t)node * 128 + c0 + i * 4]) =
                    *reinterpret_cast<float2*>(hh);
            }
        }
    }
    if (t < 128) ex[t] = cnt[t];
    __syncthreads();
    for (int o = 1; o < 128; o <<= 1) {
        int u = (t >= o && t < 128) ? ex[t - o] : 0;
        __syncthreads();
        if (t < 128) ex[t] += u;   // inclusive scan
        __syncthreads();
    }
    if (t < 128) {
        int node = b * 128 + t;
        if (node < NN)
            rowext[node] = make_int2(base + ex[t] - cnt[t], base + ex[t]);
    }
    __syncthreads();
    for (int i = t; i < cA; i += 256) {
        int w = buf[i];
        int n = (w >> 17) & 127;
        int r = atomicAdd(&run[n], 1);
        csr_src[base + ex[n] - cnt[n] + r] = w & 0x1FFFF;
    }
}

// ------ gather: 8 warp32/block, fp16 out, int2 extents --------------------
__global__ __launch_bounds__(256) void gather_kernel(const __half* __restrict__ xh,
                                                     const int2* __restrict__ rowext,
                                                     const int* __restrict__ csr_src,
                                                     __half* __restrict__ aggh) {
    int node = blockIdx.x * 8 + (threadIdx.x >> 5);
    int lane = threadIdx.x & 31;
    if (node >= NN) return;
    int2 be = rowext[node];
    int beg = be.x, end = be.y;
    float ax = 0.f, ay = 0.f, az = 0.f, aw = 0.f;
    int j = beg;
    for (; j + 4 <= end; j += 4) {
        int s0 = csr_src[j], s1 = csr_src[j + 1], s2 = csr_src[j + 2], s3 = csr_src[j + 3];
        float2 r0 = *reinterpret_cast<const float2*>(&xh[(size_t)s0 * 128 + lane * 4]);
        float2 r1 = *reinterpret_cast<const float2*>(&xh[(size_t)s1 * 128 + lane * 4]);
        float2 r2 = *reinterpret_cast<const float2*>(&xh[(size_t)s2 * 128 + lane * 4]);
        float2 r3 = *reinterpret_cast<const float2*>(&xh[(size_t)s3 * 128 + lane * 4]);
        const __half2* p0 = reinterpret_cast<const __half2*>(&r0);
        const __half2* p1 = reinterpret_cast<const __half2*>(&r1);
        const __half2* p2 = reinterpret_cast<const __half2*>(&r2);
        const __half2* p3 = reinterpret_cast<const __half2*>(&r3);
        float2 l0 = __half22float2(p0[0]), h0 = __half22float2(p0[1]);
        float2 l1 = __half22float2(p1[0]), h1 = __half22float2(p1[1]);
        float2 l2 = __half22float2(p2[0]), h2 = __half22float2(p2[1]);
        float2 l3 = __half22float2(p3[0]), h3 = __half22float2(p3[1]);
        ax += l0.x + l1.x + l2.x + l3.x;
        ay += l0.y + l1.y + l2.y + l3.y;
        az += h0.x + h1.x + h2.x + h3.x;
        aw += h0.y + h1.y + h2.y + h3.y;
    }
    for (; j < end; ++j) {
        int s = csr_src[j];
        float2 r = *reinterpret_cast<const float2*>(&xh[(size_t)s * 128 + lane * 4]);
        const __half2* p = reinterpret_cast<const __half2*>(&r);
        float2 l = __half22float2(p[0]), h = __half22float2(p[1]);
        ax += l.x; ay += l.y; az += h.x; aw += h.y;
    }
    float ni = rsqrtf(fmaxf((float)(end - beg), 1.0f));
    __half2 o01 = __floats2half2_rn(ax * ni, ay * ni);
    __half2 o23 = __floats2half2_rn(az * ni, aw * ni);
    __half2 oo[2] = {o01, o23};
    *reinterpret_cast<float2*>(&aggh[(size_t)node * 256 + lane * 4]) =
        *reinterpret_cast<float2*>(oo);
}

// ---------------- W prep: pack Wc/W1/W2 into fp16 B-fragments -------------
__global__ __launch_bounds__(256) void wprep_kernel(const float* __restrict__ Wc,
                                                    const float* __restrict__ W1,
                                                    const float* __restrict__ W2,
                                                    _Float16* __restrict__ Wf) {
    int t = blockIdx.x * 256 + threadIdx.x;
    if (t >= 3 * 4 * 8 * 64) return;
    int lane = t & 63;
    int ct = (t >> 6) & 7;
    int kt = (t >> 9) & 3;
    int layer = t >> 11;
    const float* W = (layer == 0) ? Wc : (layer == 1) ? W1 : W2;
    int c = ct * 16 + (lane & 15);
    int kbase = kt * 32 + (lane >> 4) * 8;
    f16x8 v;
#pragma unroll
    for (int j = 0; j < 8; ++j)
        v[j] = (_Float16)W[(size_t)(kbase + j) * 128 + c];
    reinterpret_cast<f16x8*>(Wf)[t] = v;
}

// ------ fused 3-layer MLP — v9: 128 rows/block, fp16, 12-step ring --------
// Wave wv owns rows [wv*32, wv*32+32) = 2 M-subtiles; W chunk feeds 16 MFMAs
// per wave per step (2x reuse vs v8); 782 blocks halve prologue overhead.
struct MlpState {
    f32x4 acc[2][8];
    float bv[3][8];
};

#define ISSUE_CHUNK(G, SLOT)                                                    \
    {                                                                           \
        _Pragma("unroll") for (int i = 0; i < 2; ++i) {                         \
            int s = wv * 2 + i;                                                 \
            size_t goff = ((size_t)((G)*8 + s)) * 1024 + (size_t)lane * 16;     \
            __builtin_amdgcn_global_load_lds(                                   \
                (const __attribute__((address_space(1))) unsigned int*)(Wb + goff), \
                (__attribute__((address_space(3))) unsigned int*)(&WL[SLOT][s * 1024]), \
                16, 0, 0);                                                      \
        }                                                                       \
    }

template <int C>
__device__ __forceinline__ void mstep(const char* __restrict__ Wb,
                                      char (&WL)[5][8192],
                                      _Float16 (&HS)[128][136],
                                      MlpState& st,
                                      float* __restrict__ Cout, int n, int row0,
                                      int lane, int wv, int mrow, int kg) {
    constexpr int layer = C >> 2;
    constexpr int kt = C & 3;
    constexpr int VM = (C <= 8) ? 6 : 2 * (11 - C);   // exact outstanding count

    asm volatile("s_waitcnt vmcnt(%0)" ::"i"(VM) : "memory");
    __builtin_amdgcn_s_barrier();

    if constexpr (C + 4 < 12) {
        ISSUE_CHUNK(C + 4, (C + 4) % 5)
    }

    if constexpr (kt == 0) {
#pragma unroll
        for (int m = 0; m < 2; ++m)
#pragma unroll
            for (int i = 0; i < 8; ++i) st.acc[m][i] = (f32x4){0.f, 0.f, 0.f, 0.f};
    }
    f16x8 a0 = *reinterpret_cast<const f16x8*>(&HS[wv * 32 + mrow][kt * 32 + kg * 8]);
    f16x8 a1 = *reinterpret_cast<const f16x8*>(&HS[wv * 32 + 16 + mrow][kt * 32 + kg * 8]);

#pragma unroll
    for (int ct = 0; ct < 8; ++ct) {
        f16x8 w = *reinterpret_cast<const f16x8*>(&WL[C % 5][(ct * 64 + lane) * 16]);
        st.acc[0][ct] = __builtin_amdgcn_mfma_f32_16x16x32_f16(a0, w, st.acc[0][ct], 0, 0, 0);
        st.acc[1][ct] = __builtin_amdgcn_mfma_f32_16x16x32_f16(a1, w, st.acc[1][ct], 0, 0, 0);
    }

    if constexpr (kt == 3) {
        if constexpr (layer < 2) {
#pragma unroll
            for (int m = 0; m < 2; ++m)
#pragma unroll
                for (int ct = 0; ct < 8; ++ct)
#pragma unroll
                    for (int r = 0; r < 4; ++r)
                        HS[wv * 32 + m * 16 + kg * 4 + r][ct * 16 + mrow] =
                            (_Float16)fmaxf(st.acc[m][ct][r] + st.bv[layer][ct], 0.f);
            asm volatile("s_waitcnt lgkmcnt(0)" ::: "memory");
        } else {
#pragma unroll
            for (int m = 0; m < 2; ++m)
#pragma unroll
                for (int ct = 0; ct < 8; ++ct)
#pragma unroll
                    for (int r = 0; r < 4; ++r) {
                        int grow = row0 + wv * 32 + m * 16 + kg * 4 + r;
                        if (grow < n)
                            Cout[(size_t)grow * 128 + ct * 16 + mrow] =
                                st.acc[m][ct][r] + st.bv[2][ct];
                    }
        }
    }
}

__global__ __launch_bounds__(256, 2) void mlp_mfma(const __half* __restrict__ Ah,
                                                   const _Float16* __restrict__ Wf,
                                                   const float* __restrict__ bc,
                                                   const float* __restrict__ b1,
                                                   const float* __restrict__ b2,
                                                   float* __restrict__ C, int n) {
    __shared__ _Float16 HS[128][136];   // 34816 B
    __shared__ char WL[5][8192];        // 40960 B
    const int tid = threadIdx.x;
    const int lane = tid & 63;
    const int wv = tid >> 6;
    const int row0 = blockIdx.x * 128;
    const int mrow = lane & 15;
    const int kg = lane >> 4;
    const char* Wb = (const char*)Wf;

    ISSUE_CHUNK(0, 0)
    ISSUE_CHUNK(1, 1)
    ISSUE_CHUNK(2, 2)
    ISSUE_CHUNK(3, 3)

    // stage 128 rows of A (already fp16; aggh row r at half-index r*256)
    {
        int r = tid >> 5;
        int c4 = (tid & 31) * 4;
#pragma unroll
        for (int i = 0; i < 16; ++i) {
            int row = i * 8 + r;
            int grow = row0 + row;
            f16x4 hv = (f16x4){(_Float16)0.f, (_Float16)0.f, (_Float16)0.f, (_Float16)0.f};
            if (grow < n)
                hv = *reinterpret_cast<const f16x4*>(&Ah[(size_t)grow * 256 + c4]);
            *reinterpret_cast<f16x4*>(&HS[row][c4]) = hv;
        }
    }
    MlpState st;
#pragma unroll
    for (int ct = 0; ct < 8; ++ct) {
        st.bv[0][ct] = bc[ct * 16 + mrow];
        st.bv[1][ct] = b1[ct * 16 + mrow];
        st.bv[2][ct] = b2[ct * 16 + mrow];
    }
    __syncthreads();   // staging reads drained before any in-place C write

    mstep<0>(Wb, WL, HS, st, C, n, row0, lane, wv, mrow, kg);
    mstep<1>(Wb, WL, HS, st, C, n, row0, lane, wv, mrow, kg);
    mstep<2>(Wb, WL, HS, st, C, n, row0, lane, wv, mrow, kg);
    mstep<3>(Wb, WL, HS, st, C, n, row0, lane, wv, mrow, kg);
    mstep<4>(Wb, WL, HS, st, C, n, row0, lane, wv, mrow, kg);
    mstep<5>(Wb, WL, HS, st, C, n, row0, lane, wv, mrow, kg);
    mstep<6>(Wb, WL, HS, st, C, n, row0, lane, wv, mrow, kg);
    mstep<7>(Wb, WL, HS, st, C, n, row0, lane, wv, mrow, kg);
    mstep<8>(Wb, WL, HS, st, C, n, row0, lane, wv, mrow, kg);
    mstep<9>(Wb, WL, HS, st, C, n, row0, lane, wv, mrow, kg);
    mstep<10>(Wb, WL, HS, st, C, n, row0, lane, wv, mrow, kg);
    mstep<11>(Wb, WL, HS, st, C, n, row0, lane, wv, mrow, kg);
}

extern "C" void kernel_launch(void* const* d_in, const int* in_sizes, int n_in,
                              void* d_out, int out_size, void* d_ws, size_t ws_size,
                              hipStream_t stream) {
    const float* x  = (const float*)d_in[0];
    const int*  src = (const int*)d_in[1];
    const int*  dst = (const int*)d_in[2];
    const float* Wc = (const float*)d_in[3];
    const float* bc = (const float*)d_in[4];
    const float* W1 = (const float*)d_in[5];
    const float* b1 = (const float*)d_in[6];
    const float* W2 = (const float*)d_in[7];
    const float* b2 = (const float*)d_in[8];
    float* out = (float*)d_out;
    __half* aggh = (__half*)d_out;   // fp16 agg interleaved: row r at half r*256

    char* p = (char*)d_ws;
    _Float16* Wf = (_Float16*)p;        p += 196608;                        // uses 98304
    __half* xh = (__half*)p;            p += (size_t)NN * 128 * 2;          // 25.6 MB
    int* tempA = (int*)p;               p += (size_t)NBK * MAXB * 4;        // 8.0 MB
    unsigned char* tempO8 = (unsigned char*)p; p += (size_t)NBK * MAXB;     // 2.0 MB
    int* cursorA  = (int*)p;            p += (size_t)NBK * 4;
    int* cursorO  = (int*)p;            p += (size_t)NBK * 4;
    int2* rowext  = (int2*)p;           p += (size_t)NN * 8;
    int* csr_src  = (int*)p;            // NBK*MAXB ints (padded, 8 MB)

    wprep_kernel<<<24, 256, 0, stream>>>(Wc, W1, W2, Wf);
    hipMemsetAsync(cursorA, 0, (size_t)2 * NBK * sizeof(int), stream);
    phase1_kernel<<<NPB, 256, 0, stream>>>(src, dst, cursorA, cursorO, tempA, tempO8);
    phase2_kernel<<<NBK, 256, 0, stream>>>(cursorA, cursorO, tempA, tempO8,
                                           x, csr_src, rowext, xh);

    // agg (norms folded) -> fp16, interleaved into d_out
    gather_kernel<<<(NN + 7) / 8, 256, 0, stream>>>(xh, rowext, csr_src, aggh);

    // fused 3-layer MLP via fp16 MFMA -> d_out f32 (block-local in-place)
    mlp_mfma<<<(NN + 127) / 128, 256, 0, stream>>>(aggh, Wf, bc, b1, b2, out, NN);
}